// Round 12
// baseline (189.566 us; speedup 1.0000x reference)
//
#include <hip/hip_runtime.h>
#include <math.h>

#define N_ROWS 4096
#define D_DIM  256
#define INV_T  (1.0f / 0.07f)
#define NW     64                     // u64 words per packed mask row

typedef _Float16 half8 __attribute__((ext_vector_type(8)));
typedef _Float16 half4 __attribute__((ext_vector_type(4)));
typedef float    f32x4 __attribute__((ext_vector_type(4)));
typedef unsigned long long u64;
typedef unsigned char u8;

#define GLOAD_LDS(gp, lp) \
    __builtin_amdgcn_global_load_lds( \
        (const __attribute__((address_space(1))) void*)(gp), \
        (__attribute__((address_space(3))) void*)(lp), 16, 0, 0)

// ---------------------------------------------------------------------------
// normalize_k (verified round-1 kernel): row-normalize -> fp16, zero accum.
// ---------------------------------------------------------------------------
__global__ __launch_bounds__(256) void normalize_k(const float* __restrict__ f,
                                                   _Float16* __restrict__ fnh,
                                                   float* __restrict__ accum) {
    const int t   = threadIdx.x;
    const int gid = blockIdx.x * 256 + t;
    if (gid < 3 * N_ROWS) accum[gid] = 0.0f;

    const int lane = t & 63;
    const int row  = blockIdx.x * 4 + (t >> 6);
    float4 v = ((const float4*)(f + (size_t)row * D_DIM))[lane];
    float s = v.x * v.x + v.y * v.y + v.z * v.z + v.w * v.w;
    #pragma unroll
    for (int off = 32; off > 0; off >>= 1) s += __shfl_xor(s, off, 64);
    float rn = 1.0f / fmaxf(sqrtf(s), 1e-8f);
    half4 h;
    h.x = (_Float16)(v.x * rn);
    h.y = (_Float16)(v.y * rn);
    h.z = (_Float16)(v.z * rn);
    h.w = (_Float16)(v.w * rn);
    *(half4*)(fnh + (size_t)row * D_DIM + lane * 4) = h;
}

// ---------------------------------------------------------------------------
// prep_k v6b: mask compress via global_load_lds DMA staging.
// Theory (round 9): five register-path streamers all pinned at 2.3-3.2 TB/s;
// VGPR counts (12-48) prove the compiler ALWAYS narrows register-held load
// batches to ~1 in flight per wave -> per-wave serial latency chains.
// global_load_lds has no VGPR destination, so the batch cannot be narrowed:
// each wave issues its ENTIRE 16 KB row as 16 DMA loads (64 KB/block in
// flight, ~14x Little's-law need).
// v6b (rounds 10/11 container failures; hedge): counted vmcnt drain replaced
// with ONE __syncthreads() -- the compiler's barrier drain (s_waitcnt
// vmcnt(0) before s_barrier) waits for the whole batch, so the 16 loads
// still ride together; consumption then runs purely from LDS.  No inline
// asm, no sched_barrier.
// Consume: 4 compares -> nibble -> per-lane u64 (v2 nibble layout: lane L,
// chunk c covers cols {256c+4L+e}, nibble at bits [4c..4c+3]), one u64
// store per lane.  Diagonal (col==row) folded in.  Output consumed by the
// round-5-verified v11 epilogue formulas.
// ---------------------------------------------------------------------------
__global__ __launch_bounds__(256) void prep_k(const float* __restrict__ pm,
                                              const float* __restrict__ nm,
                                              u64* __restrict__ P,
                                              u64* __restrict__ Nm) {
    __shared__ __align__(16) float stage[4][16][256];   // 64 KB: wave-private slices

    const int t    = threadIdx.x;
    const int lane = t & 63;
    const int w    = t >> 6;                 // wave 0..3
    const int task = blockIdx.x * 4 + w;     // 0..8191
    const int row  = task & (N_ROWS - 1);
    const int isN  = task >> 12;             // 0 = pm, 1 = nm

    const float* src = (isN ? nm : pm) + (size_t)row * N_ROWS;

    // ---- issue the whole row as 16 DMA loads (stay in flight together) ----
    #pragma unroll
    for (int c = 0; c < 16; ++c)
        GLOAD_LDS(src + c * 256 + lane * 4, &stage[w][c][0]);

    // ---- single drain: compiler emits s_waitcnt vmcnt(0) before barrier ----
    __syncthreads();

    // ---- consume from LDS (pure LDS+VALU from here) ----
    u64 acc = 0;
    #pragma unroll
    for (int c = 0; c < 16; ++c) {
        const float4 v = *(const float4*)&stage[w][c][lane * 4];
        const int col0 = c * 256 + lane * 4;
        unsigned nib = 0;
        nib |= (v.x != 0.f && col0 + 0 != row) ? 1u : 0u;
        nib |= (v.y != 0.f && col0 + 1 != row) ? 2u : 0u;
        nib |= (v.z != 0.f && col0 + 2 != row) ? 4u : 0u;
        nib |= (v.w != 0.f && col0 + 3 != row) ? 8u : 0u;
        acc |= ((u64)nib) << (4 * c);
    }
    (isN ? Nm : P)[(size_t)row * NW + lane] = acc;
}

// ---------------------------------------------------------------------------
// fused_k v14: 128x128 tile GEMM (verified rounds 6/8/9: 4 waves, 4x4
// fragments of 16x16x32, 32 KB LDS, grid 32x32) + u64 nibble-mask epilogue
// (verified round 5 as v11):
//   col = bx*128 + wc*64 + jt*16 + grp*4 + e
//   word L = (bx&1)*32 + wc*16 + jt*4 + grp, nibble shift csh = (bx>>1)*4.
// P/N are 2 MB each -> L2-resident.
// ---------------------------------------------------------------------------
__global__ __launch_bounds__(256) void fused_k(const _Float16* __restrict__ fnh,
                                               const u64* __restrict__ P,
                                               const u64* __restrict__ Nm,
                                               float* __restrict__ accum) {
    __shared__ __align__(16) _Float16 lds[2 * 128 * 64];   // 32 KB
    _Float16* As = lds;               // [128][64]
    _Float16* Bs = lds + 128 * 64;    // [128][64]

    const int t    = threadIdx.x;
    const int lane = t & 63;
    const int w    = t >> 6;        // wave 0..3
    const int wr   = w >> 1;        // i-half (64 rows)
    const int wc   = w & 1;         // j-half (64 cols)
    const int bx   = blockIdx.x;
    const int i0   = blockIdx.y * 128;
    const int j0   = bx * 128;
    const int l15  = lane & 15;
    const int grp  = lane >> 4;

    const int srow  = t >> 3;                          // 0..31
    const int sslot = ((t & 7) ^ ((t >> 3) & 7)) * 8;  // swizzled granule

    f32x4 acc[4][4];  // [jt][it]
    #pragma unroll
    for (int a = 0; a < 4; ++a)
        #pragma unroll
        for (int b = 0; b < 4; ++b)
            acc[a][b] = (f32x4){0.f, 0.f, 0.f, 0.f};

    for (int k0 = 0; k0 < D_DIM; k0 += 64) {
        #pragma unroll
        for (int q = 0; q < 4; ++q) {
            GLOAD_LDS(fnh + (size_t)(i0 + q * 32 + srow) * D_DIM + k0 + sslot,
                      &As[q * 2048 + w * 512]);
            GLOAD_LDS(fnh + (size_t)(j0 + q * 32 + srow) * D_DIM + k0 + sslot,
                      &Bs[q * 2048 + w * 512]);
        }
        __syncthreads();

        #pragma unroll
        for (int kk = 0; kk < 2; ++kk) {
            half8 aj[4], bi[4];
            #pragma unroll
            for (int jt = 0; jt < 4; ++jt) {
                const int r = wc * 64 + jt * 16 + l15;
                aj[jt] = *(const half8*)&Bs[r * 64 + (((kk * 4 + grp) ^ (r & 7)) << 3)];
            }
            #pragma unroll
            for (int it = 0; it < 4; ++it) {
                const int r = wr * 64 + it * 16 + l15;
                bi[it] = *(const half8*)&As[r * 64 + (((kk * 4 + grp) ^ (r & 7)) << 3)];
            }
            #pragma unroll
            for (int jt = 0; jt < 4; ++jt)
                #pragma unroll
                for (int it = 0; it < 4; ++it)
                    acc[jt][it] = __builtin_amdgcn_mfma_f32_16x16x32_f16(
                        aj[jt], bi[it], acc[jt][it], 0, 0, 0);
        }
        __syncthreads();
    }

    // ---- epilogue: u64 nibble-mask loads (L2), exp/fma, reduce over grp ----
    const int mrow0 = i0 + wr * 64 + l15;
    const int Lb    = (bx & 1) * 32 + wc * 16 + grp;   // + jt*4
    const int csh   = (bx >> 1) * 4;                   // nibble shift

    #pragma unroll
    for (int it = 0; it < 4; ++it) {
        const int i = mrow0 + it * 16;
        float negp = 0.f, posp = 0.f, np = 0.f;
        #pragma unroll
        for (int jt = 0; jt < 4; ++jt) {
            const u64 wpv = P[(size_t)i * NW + Lb + jt * 4];
            const u64 wnv = Nm[(size_t)i * NW + Lb + jt * 4];
            const unsigned nibP = (unsigned)(wpv >> csh) & 0xFu;
            const unsigned nibN = (unsigned)(wnv >> csh) & 0xFu;
            #pragma unroll
            for (int e = 0; e < 4; ++e) {
                const float cs = acc[jt][it][e] * INV_T;
                const float pf = (float)((nibP >> e) & 1u);
                const float nf = (float)((nibN >> e) & 1u);
                negp = fmaf(__expf(cs), nf, negp);
                posp = fmaf(cs, pf, posp);
                np  += pf;
            }
        }
        negp += __shfl_xor(negp, 16, 64);
        posp += __shfl_xor(posp, 16, 64);
        np   += __shfl_xor(np,   16, 64);
        negp += __shfl_xor(negp, 32, 64);
        posp += __shfl_xor(posp, 32, 64);
        np   += __shfl_xor(np,   32, 64);
        if (grp == 0) {
            atomicAdd(&accum[i], negp);
            atomicAdd(&accum[N_ROWS + i], posp);
            atomicAdd(&accum[2 * N_ROWS + i], np);
        }
    }
}

// ---------------------------------------------------------------------------
// final_k: reduction over rows -> scalar loss
// ---------------------------------------------------------------------------
__global__ __launch_bounds__(256) void final_k(const float* __restrict__ accum,
                                               float* __restrict__ out) {
    const int t = threadIdx.x;
    float s = 0.f;
    for (int i = t; i < N_ROWS; i += 256) {
        float neg  = accum[i];
        float posc = accum[N_ROWS + i];
        float np   = accum[2 * N_ROWS + i];
        float term = (np > 0.f) ? (posc - np * logf(fmaxf(neg, 1e-30f))) / np : 0.f;
        s += term;
    }
    #pragma unroll
    for (int off = 32; off > 0; off >>= 1) s += __shfl_xor(s, off, 64);
    __shared__ float wsum[4];
    if ((t & 63) == 0) wsum[t >> 6] = s;
    __syncthreads();
    if (t == 0) {
        float tot = wsum[0] + wsum[1] + wsum[2] + wsum[3];
        out[0] = -tot / (float)N_ROWS;
    }
}

// ---------------------------------------------------------------------------
// ws layout: fnh 2 MB | accum 64 KB | P 2 MB | N 2 MB  (~6.2 MB total)
// ---------------------------------------------------------------------------
extern "C" void kernel_launch(void* const* d_in, const int* in_sizes, int n_in,
                              void* d_out, int out_size, void* d_ws, size_t ws_size,
                              hipStream_t stream) {
    const float* feat = (const float*)d_in[0];
    const float* pm   = (const float*)d_in[1];
    const float* nm   = (const float*)d_in[2];
    float* out = (float*)d_out;

    const size_t FNH_B = (size_t)N_ROWS * D_DIM * sizeof(_Float16);  // 2 MB
    const size_t ACC_B = 65536;
    const size_t PKB   = (size_t)N_ROWS * NW * sizeof(u64);          // 2 MB

    _Float16* fnh = (_Float16*)d_ws;
    float* accum  = (float*)((char*)d_ws + FNH_B);
    u64* P        = (u64*)((char*)d_ws + FNH_B + ACC_B);
    u64* Nm       = (u64*)((char*)d_ws + FNH_B + ACC_B + PKB);

    normalize_k<<<N_ROWS / 4, 256, 0, stream>>>(feat, fnh, accum);
    prep_k<<<2048, 256, 0, stream>>>(pm, nm, P, Nm);

    dim3 grid(N_ROWS / 128, N_ROWS / 128);
    fused_k<<<grid, 256, 0, stream>>>(fnh, P, Nm, accum);

    final_k<<<1, 256, 0, stream>>>(accum, out);
}

// Round 13
// 180.846 us; speedup vs baseline: 1.0482x; 1.0482x over previous
//
#include <hip/hip_runtime.h>
#include <math.h>

#define N_ROWS 4096
#define D_DIM  256
#define INV_T  (1.0f / 0.07f)

typedef _Float16 half8 __attribute__((ext_vector_type(8)));
typedef _Float16 half4 __attribute__((ext_vector_type(4)));
typedef float    f32x4 __attribute__((ext_vector_type(4)));

#define GLOAD_LDS(gp, lp) \
    __builtin_amdgcn_global_load_lds( \
        (const __attribute__((address_space(1))) void*)(gp), \
        (__attribute__((address_space(3))) void*)(lp), 16, 0, 0)

// ---------------------------------------------------------------------------
// K1: row-normalize features -> fp16 (one wave per row) + zero accum.
// ---------------------------------------------------------------------------
__global__ __launch_bounds__(256) void normalize_k(const float* __restrict__ f,
                                                   _Float16* __restrict__ fnh,
                                                   float* __restrict__ accum) {
    const int t   = threadIdx.x;
    const int gid = blockIdx.x * 256 + t;
    if (gid < 3 * N_ROWS) accum[gid] = 0.0f;

    const int lane = t & 63;
    const int row  = blockIdx.x * 4 + (t >> 6);
    float4 v = ((const float4*)(f + (size_t)row * D_DIM))[lane];
    float s = v.x * v.x + v.y * v.y + v.z * v.z + v.w * v.w;
    #pragma unroll
    for (int off = 32; off > 0; off >>= 1) s += __shfl_xor(s, off, 64);
    float rn = 1.0f / fmaxf(sqrtf(s), 1e-8f);
    half4 h;
    h.x = (_Float16)(v.x * rn);
    h.y = (_Float16)(v.y * rn);
    h.z = (_Float16)(v.z * rn);
    h.w = (_Float16)(v.w * rn);
    *(half4*)(fnh + (size_t)row * D_DIM + lane * 4) = h;
}

// ---------------------------------------------------------------------------
// fused_k: the round-2 session champion (55.6 us, total 173.1) with ONE
// change: the 8 mask prefetch loads are NONTEMPORAL (nt -> no L2 retention).
// Theory: all six mask-stream variants (incl. 64KB/block global_load_lds
// DMA, r12) pinned at 2.3-3.2 TB/s regardless of width/depth/occupancy/
// source(HBM vs L3) -- the one shared property left is L2 allocation of a
// 128 MB stream thrashing 4 MB/XCD L2s.  nt is the only untested policy.
// Everything else is byte-identical to the verified round-2 kernel:
// 64x64 tiles, mask prefetch at block start riding under the GEMM, bitmask
// compression after the first barrier, register epilogue, butterfly over
// grp, 16-lane atomics.
// ---------------------------------------------------------------------------
__global__ __launch_bounds__(256) void fused_k(const _Float16* __restrict__ fnh,
                                               const float* __restrict__ pm,
                                               const float* __restrict__ nm,
                                               float* __restrict__ accum) {
    __shared__ __align__(16) _Float16 lds[64 * 128];   // 16 KB
    _Float16* As = lds;             // [64][64] halfs during K-loop
    _Float16* Bs = lds + 64 * 64;   // [64][64] halfs during K-loop

    const int t    = threadIdx.x;
    const int lane = t & 63;
    const int w    = t >> 6;        // wave 0..3
    const int wr   = w >> 1;        // i-half of tile
    const int wc   = w & 1;         // j-half of tile
    const int i0   = blockIdx.y * 64;
    const int j0   = blockIdx.x * 64;
    const int l15  = lane & 15;
    const int grp  = lane >> 4;

    // staging: 8 lanes-worth of granules per row, XOR-swizzled
    const int srow = t >> 3;                          // 0..31 per issue
    const int sslot = ((t & 7) ^ ((t >> 3) & 7)) * 8; // swizzled 16B granule (halfs)

    // ---- mask prefetch: 8 nt float4 loads, in flight during whole GEMM ----
    const int mrow0 = i0 + wr * 32 + l15;
    const int mcol0 = j0 + wc * 32 + grp * 4;
    f32x4 pmv[2][2], nmv[2][2];
    #pragma unroll
    for (int it = 0; it < 2; ++it)
        #pragma unroll
        for (int jt = 0; jt < 2; ++jt) {
            const size_t off = (size_t)(mrow0 + it * 16) * N_ROWS + (mcol0 + jt * 16);
            pmv[it][jt] = __builtin_nontemporal_load((const f32x4*)(pm + off));
            nmv[it][jt] = __builtin_nontemporal_load((const f32x4*)(nm + off));
        }

    f32x4 acc[2][2];  // [jt][it]
    #pragma unroll
    for (int a = 0; a < 2; ++a)
        #pragma unroll
        for (int b = 0; b < 2; ++b)
            acc[a][b] = (f32x4){0.f, 0.f, 0.f, 0.f};

    unsigned pmb = 0, nmb = 0;   // 16 bits each: b = it*8 + jt*4 + e

    #pragma unroll
    for (int k0 = 0; k0 < D_DIM; k0 += 64) {
        #pragma unroll
        for (int q = 0; q < 2; ++q) {
            GLOAD_LDS(fnh + (size_t)(i0 + q * 32 + srow) * D_DIM + k0 + sslot,
                      &As[q * 2048 + w * 512]);
            GLOAD_LDS(fnh + (size_t)(j0 + q * 32 + srow) * D_DIM + k0 + sslot,
                      &Bs[q * 2048 + w * 512]);
        }
        __syncthreads();   // drains staging AND (first iter) the mask loads

        if (k0 == 0) {
            // ---- compress masks to bits; diagonal (i==j) cleared here ----
            #pragma unroll
            for (int it = 0; it < 2; ++it)
                #pragma unroll
                for (int jt = 0; jt < 2; ++jt) {
                    const int i = mrow0 + it * 16;
                    const int jb = mcol0 + jt * 16;
                    #pragma unroll
                    for (int e = 0; e < 4; ++e) {
                        const int b = it * 8 + jt * 4 + e;
                        const unsigned keep = (unsigned)(i != (jb + e));
                        pmb |= (((unsigned)(pmv[it][jt][e] != 0.f) & keep) << b);
                        nmb |= (((unsigned)(nmv[it][jt][e] != 0.f) & keep) << b);
                    }
                }
        }

        #pragma unroll
        for (int kk = 0; kk < 2; ++kk) {
            half8 aj[2], bi[2];
            #pragma unroll
            for (int jt = 0; jt < 2; ++jt) {
                const int r = wc * 32 + jt * 16 + l15;
                aj[jt] = *(const half8*)&Bs[r * 64 + (((kk * 4 + grp) ^ (r & 7)) << 3)];
            }
            #pragma unroll
            for (int it = 0; it < 2; ++it) {
                const int r = wr * 32 + it * 16 + l15;
                bi[it] = *(const half8*)&As[r * 64 + (((kk * 4 + grp) ^ (r & 7)) << 3)];
            }
            #pragma unroll
            for (int jt = 0; jt < 2; ++jt)
                #pragma unroll
                for (int it = 0; it < 2; ++it)
                    acc[jt][it] = __builtin_amdgcn_mfma_f32_16x16x32_f16(
                        aj[jt], bi[it], acc[jt][it], 0, 0, 0);
        }
        __syncthreads();
    }

    // ---- streaming from registers, butterfly over grp, atomics ----
    #pragma unroll
    for (int it = 0; it < 2; ++it) {
        float negp = 0.f, posp = 0.f, np = 0.f;
        #pragma unroll
        for (int jt = 0; jt < 2; ++jt)
            #pragma unroll
            for (int e = 0; e < 4; ++e) {
                const int b = it * 8 + jt * 4 + e;
                const float cs = acc[jt][it][e] * INV_T;
                const float pf = (float)((pmb >> b) & 1u);
                const float nf = (float)((nmb >> b) & 1u);
                negp = fmaf(__expf(cs), nf, negp);
                posp = fmaf(cs, pf, posp);
                np  += pf;
            }
        #pragma unroll
        for (int off = 16; off < 64; off <<= 1) {
            negp += __shfl_xor(negp, off, 64);
            posp += __shfl_xor(posp, off, 64);
            np   += __shfl_xor(np,   off, 64);
        }
        if (grp == 0) {            // lanes 0..15: one row each
            const int i = mrow0 + it * 16;
            atomicAdd(&accum[i], negp);
            atomicAdd(&accum[N_ROWS + i], posp);
            atomicAdd(&accum[2 * N_ROWS + i], np);
        }
    }
}

// ---------------------------------------------------------------------------
// K3: final reduction over rows -> scalar loss
// ---------------------------------------------------------------------------
__global__ __launch_bounds__(256) void final_k(const float* __restrict__ accum,
                                               float* __restrict__ out) {
    const int t = threadIdx.x;
    float s = 0.f;
    for (int i = t; i < N_ROWS; i += 256) {
        float neg  = accum[i];
        float posc = accum[N_ROWS + i];
        float np   = accum[2 * N_ROWS + i];
        float term = (np > 0.f) ? (posc - np * logf(fmaxf(neg, 1e-30f))) / np : 0.f;
        s += term;
    }
    #pragma unroll
    for (int off = 32; off > 0; off >>= 1) s += __shfl_xor(s, off, 64);
    __shared__ float wsum[4];
    if ((t & 63) == 0) wsum[t >> 6] = s;
    __syncthreads();
    if (t == 0) {
        float tot = wsum[0] + wsum[1] + wsum[2] + wsum[3];
        out[0] = -tot / (float)N_ROWS;
    }
}

// ---------------------------------------------------------------------------
extern "C" void kernel_launch(void* const* d_in, const int* in_sizes, int n_in,
                              void* d_out, int out_size, void* d_ws, size_t ws_size,
                              hipStream_t stream) {
    const float* feat = (const float*)d_in[0];
    const float* pm   = (const float*)d_in[1];
    const float* nm   = (const float*)d_in[2];
    float* out = (float*)d_out;

    _Float16* fnh = (_Float16*)d_ws;                          // 2 MB
    float* accum  = (float*)(fnh + (size_t)N_ROWS * D_DIM);   // 48 KB

    normalize_k<<<N_ROWS / 4, 256, 0, stream>>>(feat, fnh, accum);

    dim3 grid(N_ROWS / 64, N_ROWS / 64);
    fused_k<<<grid, 256, 0, stream>>>(fnh, pm, nm, accum);

    final_k<<<1, 256, 0, stream>>>(accum, out);
}